// Round 1
// baseline (103.038 us; speedup 1.0000x reference)
//
#include <hip/hip_runtime.h>

#define S_LEN 2048
#define DMODEL 1024
#define NHEADS 16
#define DKH 64
#define WIN 256

typedef unsigned short u16;
typedef unsigned int u32;
typedef __attribute__((ext_vector_type(8))) __bf16 bf16x8;
typedef __attribute__((ext_vector_type(4))) float f32x4;
typedef __attribute__((ext_vector_type(8))) u16 u16x8;
typedef __attribute__((ext_vector_type(4))) u16 u16x4;

__device__ __forceinline__ u16 f2bf(float f) {
  u32 u = __builtin_bit_cast(u32, f);
  u += 0x7fffu + ((u >> 16) & 1u);   // round-to-nearest-even
  return (u16)(u >> 16);
}

#define GLDS16(g, l) __builtin_amdgcn_global_load_lds( \
    (const __attribute__((address_space(1))) void*)(g), \
    (__attribute__((address_space(3))) void*)(l), 16, 0, 0)

// ---------------- cast f32 -> bf16 ----------------
__global__ __launch_bounds__(256) void cast_f32_bf16(const float* __restrict__ in,
                                                     u16* __restrict__ out, int n) {
  int i = (blockIdx.x * 256 + threadIdx.x) * 4;
  if (i >= n) return;
  float4 v = *(const float4*)(in + i);
  u16x4 o = { f2bf(v.x), f2bf(v.y), f2bf(v.z), f2bf(v.w) };
  *(u16x4*)(out + i) = o;
}

// ---------------- NT GEMM: C[M,N] = A[M,K] * Bt[N,K]^T + bias ----------------
// 128x128 tile, BK=32, 256 threads (4 waves, each 64x64), double-buffered LDS,
// global_load_lds width-16 staging. blockIdx.z selects among 3 weight sets.
template<int OUTF32>
__global__ __launch_bounds__(256) void gemm_nt(
    const u16* __restrict__ A,
    const u16* __restrict__ B0, const u16* __restrict__ B1, const u16* __restrict__ B2,
    const float* __restrict__ bias0, const float* __restrict__ bias1, const float* __restrict__ bias2,
    void* __restrict__ C0, void* __restrict__ C1, void* __restrict__ C2,
    const int M, const int N, const int K)
{
  const u16* Bt; const float* bias; void* C;
  if (blockIdx.z == 0)      { Bt = B0; bias = bias0; C = C0; }
  else if (blockIdx.z == 1) { Bt = B1; bias = bias1; C = C1; }
  else                      { Bt = B2; bias = bias2; C = C2; }

  __shared__ u16 As[2][128 * 32];
  __shared__ u16 Bs[2][128 * 32];

  const int t = threadIdx.x;
  const int row0 = blockIdx.x * 128;
  const int col0 = blockIdx.y * 128;
  const int lane = t & 63, lo = lane & 15, hi = lane >> 4;
  const int wv = t >> 6;
  const int wr = (wv >> 1) * 64, wc = (wv & 1) * 64;

  f32x4 acc[4][4];
  #pragma unroll
  for (int i = 0; i < 4; ++i)
    #pragma unroll
    for (int j = 0; j < 4; ++j) acc[i][j] = (f32x4)0.0f;

  const int NT = K >> 5;

  auto stage = [&](int buf, int kt) {
    const int kof = kt * 32;
    #pragma unroll
    for (int c = 0; c < 2; ++c) {
      const int off = t * 16 + c * 4096;     // byte offset in 128x32 bf16 tile (64B rows)
      const int r = off >> 6;
      const int ke = (off & 63) >> 1;
      GLDS16(A  + (size_t)(row0 + r) * K + (kof + ke), (u16*)As + buf * (128 * 32) + (off >> 1));
      GLDS16(Bt + (size_t)(col0 + r) * K + (kof + ke), (u16*)Bs + buf * (128 * 32) + (off >> 1));
    }
  };

  stage(0, 0);
  int cur = 0;
  for (int kt = 0; kt < NT; ++kt) {
    __syncthreads();                    // drains vmcnt -> buf[cur] staged; protects buf[cur^1]
    if (kt + 1 < NT) stage(cur ^ 1, kt + 1);
    bf16x8 af[4], bfr[4];
    #pragma unroll
    for (int mi = 0; mi < 4; ++mi)
      af[mi] = *(const bf16x8*)&As[cur][(wr + mi * 16 + lo) * 32 + hi * 8];
    #pragma unroll
    for (int ni = 0; ni < 4; ++ni)
      bfr[ni] = *(const bf16x8*)&Bs[cur][(wc + ni * 16 + lo) * 32 + hi * 8];
    #pragma unroll
    for (int mi = 0; mi < 4; ++mi)
      #pragma unroll
      for (int ni = 0; ni < 4; ++ni)
        acc[mi][ni] = __builtin_amdgcn_mfma_f32_16x16x32_bf16(af[mi], bfr[ni], acc[mi][ni], 0, 0, 0);
    cur ^= 1;
  }

  #pragma unroll
  for (int mi = 0; mi < 4; ++mi) {
    #pragma unroll
    for (int ni = 0; ni < 4; ++ni) {
      const int col = col0 + wc + ni * 16 + lo;
      const float bv = bias[col];
      #pragma unroll
      for (int r = 0; r < 4; ++r) {
        const int row = row0 + wr + mi * 16 + hi * 4 + r;
        const float v = acc[mi][ni][r] + bv;
        if (OUTF32) ((float*)C)[(size_t)row * N + col] = v;
        else        ((u16*)C)[(size_t)row * N + col] = f2bf(v);
      }
    }
  }
}

// ---------------- windowed causal attention ----------------
// grid (S/64, H, B); block 256 (4 waves x 16 query rows).
// For q-tile [q0, q0+63]: 5 key chunks of 64 covering [q0-256, q0+63].
// Online softmax in MFMA C-layout. LDS rows are 128B -> XOR swizzle (T2).
__device__ __forceinline__ int swz(int row, int col) {   // ushort index, [*][64] tiles
  int byte = (row << 7) + (col << 1);
  byte ^= (row & 7) << 4;
  return byte >> 1;
}

__global__ __launch_bounds__(256) void attn_win(const u16* __restrict__ Q,
                                                const u16* __restrict__ K,
                                                const u16* __restrict__ V,
                                                u16* __restrict__ O) {
  const int qt = blockIdx.x, h = blockIdx.y, b = blockIdx.z;
  const int q0 = qt * 64;
  const int t = threadIdx.x;
  const int wv = t >> 6, lane = t & 63, lo = lane & 15, hi = lane >> 4;

  __shared__ u16 Qs[64 * 64];
  __shared__ u16 Ks[64 * 64];
  __shared__ u16 Vt[64 * 64];
  __shared__ u16 Ps[4][16 * 64];

  const size_t base = ((size_t)b * S_LEN) * DMODEL + h * DKH;

  // Q tile -> LDS (linear, via global_load_lds), read once into regs
  #pragma unroll
  for (int c = 0; c < 2; ++c) {
    const int off = t * 16 + c * 4096;       // byte in 64x64 bf16 tile (128B rows)
    const int r = off >> 7, ce = (off & 127) >> 1;
    GLDS16(Q + base + (size_t)(q0 + r) * DMODEL + ce, (u16*)Qs + (off >> 1));
  }
  __syncthreads();

  bf16x8 qf[2];
  #pragma unroll
  for (int kq = 0; kq < 2; ++kq)
    qf[kq] = *(const bf16x8*)&Qs[(wv * 16 + lo) * 64 + kq * 32 + hi * 8];

  f32x4 oacc[4];
  #pragma unroll
  for (int i = 0; i < 4; ++i) oacc[i] = (f32x4)0.0f;
  float m_r[4] = {-1e30f, -1e30f, -1e30f, -1e30f};
  float l_r[4] = {0.f, 0.f, 0.f, 0.f};

  const int vrow = t >> 2;
  const int vc0  = (t & 3) * 16;

  for (int kt = 0; kt < 5; ++kt) {
    const int kstart = q0 - 256 + kt * 64;
    if (kstart + 63 < 0) continue;           // uniform across block
    __syncthreads();                          // prev chunk compute done before overwrite

    {
      const int jg = kstart + vrow;
      if (jg >= 0) {
        const u16* srcK = K + base + (size_t)jg * DMODEL + vc0;
        u16x8 k0 = *(const u16x8*)(srcK);
        u16x8 k1 = *(const u16x8*)(srcK + 8);
        *(u16x8*)&Ks[swz(vrow, vc0)]     = k0;
        *(u16x8*)&Ks[swz(vrow, vc0 + 8)] = k1;
        const u16* srcV = V + base + (size_t)jg * DMODEL + vc0;
        u16x8 v0 = *(const u16x8*)(srcV);
        u16x8 v1 = *(const u16x8*)(srcV + 8);
        #pragma unroll
        for (int e = 0; e < 8; ++e) {
          Vt[swz(vc0 + e, vrow)]     = v0[e];
          Vt[swz(vc0 + 8 + e, vrow)] = v1[e];
        }
      } else {
        u16x8 z = (u16x8)0;
        *(u16x8*)&Ks[swz(vrow, vc0)]     = z;
        *(u16x8*)&Ks[swz(vrow, vc0 + 8)] = z;
        #pragma unroll
        for (int e = 0; e < 16; ++e) Vt[swz(vc0 + e, vrow)] = 0;
      }
    }
    __syncthreads();

    // S = Q K^T
    f32x4 sfr[4];
    #pragma unroll
    for (int ni = 0; ni < 4; ++ni) {
      sfr[ni] = (f32x4)0.0f;
      #pragma unroll
      for (int kq = 0; kq < 2; ++kq) {
        bf16x8 kf = *(const bf16x8*)&Ks[swz(ni * 16 + lo, kq * 32 + hi * 8)];
        sfr[ni] = __builtin_amdgcn_mfma_f32_16x16x32_bf16(qf[kq], kf, sfr[ni], 0, 0, 0);
      }
    }

    // mask + scale + per-row chunk max
    float sv[4][4], cmax[4] = {-1e30f, -1e30f, -1e30f, -1e30f};
    const int i0 = q0 + wv * 16 + hi * 4;
    #pragma unroll
    for (int ni = 0; ni < 4; ++ni) {
      const int j = kstart + ni * 16 + lo;
      #pragma unroll
      for (int r = 0; r < 4; ++r) {
        const int i = i0 + r;
        float x = sfr[ni][r] * 0.125f;
        const bool ok = (j >= 0) & (j <= i) & (i - j < WIN);
        x = ok ? x : -1e30f;
        sv[ni][r] = x;
        cmax[r] = fmaxf(cmax[r], x);
      }
    }
    #pragma unroll
    for (int d = 1; d < 16; d <<= 1) {
      #pragma unroll
      for (int r = 0; r < 4; ++r) cmax[r] = fmaxf(cmax[r], __shfl_xor(cmax[r], d));
    }

    // online-softmax update
    float pr[4][4], rsum[4];
    #pragma unroll
    for (int r = 0; r < 4; ++r) {
      const float mnew = fmaxf(m_r[r], cmax[r]);
      const float sc = __expf(m_r[r] - mnew);
      m_r[r] = mnew;
      l_r[r] *= sc;
      #pragma unroll
      for (int ni = 0; ni < 4; ++ni) oacc[ni][r] *= sc;
      float s = 0.f;
      #pragma unroll
      for (int ni = 0; ni < 4; ++ni) {
        const float p = __expf(sv[ni][r] - mnew);
        pr[ni][r] = p;
        s += p;
      }
      rsum[r] = s;
    }
    #pragma unroll
    for (int d = 1; d < 16; d <<= 1) {
      #pragma unroll
      for (int r = 0; r < 4; ++r) rsum[r] += __shfl_xor(rsum[r], d);
    }
    #pragma unroll
    for (int r = 0; r < 4; ++r) l_r[r] += rsum[r];

    // P -> per-wave LDS (C-layout write), re-read as A-fragments
    #pragma unroll
    for (int ni = 0; ni < 4; ++ni)
      #pragma unroll
      for (int r = 0; r < 4; ++r)
        Ps[wv][swz(hi * 4 + r, ni * 16 + lo)] = f2bf(pr[ni][r]);

    bf16x8 pa[2];
    #pragma unroll
    for (int kp = 0; kp < 2; ++kp)
      pa[kp] = *(const bf16x8*)&Ps[wv][swz(lo, kp * 32 + hi * 8)];
    #pragma unroll
    for (int ni = 0; ni < 4; ++ni) {
      #pragma unroll
      for (int kp = 0; kp < 2; ++kp) {
        bf16x8 vf = *(const bf16x8*)&Vt[swz(ni * 16 + lo, kp * 32 + hi * 8)];
        oacc[ni] = __builtin_amdgcn_mfma_f32_16x16x32_bf16(pa[kp], vf, oacc[ni], 0, 0, 0);
      }
    }
  }

  #pragma unroll
  for (int ni = 0; ni < 4; ++ni) {
    #pragma unroll
    for (int r = 0; r < 4; ++r) {
      const int row = q0 + wv * 16 + hi * 4 + r;
      O[base + (size_t)row * DMODEL + ni * 16 + lo] = f2bf(oacc[ni][r] / l_r[r]);
    }
  }
}

// ---------------- launch ----------------
extern "C" void kernel_launch(void* const* d_in, const int* in_sizes, int n_in,
                              void* d_out, int out_size, void* d_ws, size_t ws_size,
                              hipStream_t stream) {
  const float* x  = (const float*)d_in[0];
  const float* wq = (const float*)d_in[1];
  const float* bq = (const float*)d_in[2];
  const float* wk = (const float*)d_in[3];
  const float* bk = (const float*)d_in[4];
  const float* wvp = (const float*)d_in[5];
  const float* bv = (const float*)d_in[6];
  const float* wo = (const float*)d_in[7];
  const float* bo = (const float*)d_in[8];
  float* out = (float*)d_out;

  char* ws = (char*)d_ws;
  const size_t MB = 1024 * 1024;
  u16* xb  = (u16*)(ws);
  u16* wqb = (u16*)(ws + 8 * MB);
  u16* wkb = (u16*)(ws + 10 * MB);
  u16* wvb = (u16*)(ws + 12 * MB);
  u16* wob = (u16*)(ws + 14 * MB);
  u16* Qb  = (u16*)(ws + 16 * MB);
  u16* Kb  = (u16*)(ws + 24 * MB);
  u16* Vb  = (u16*)(ws + 32 * MB);
  u16* Ob  = (u16*)(ws + 40 * MB);   // ends at 48 MB

  const int nx = 2 * S_LEN * DMODEL;       // 4194304
  const int nw = DMODEL * DMODEL;          // 1048576
  cast_f32_bf16<<<nx / 4 / 256, 256, 0, stream>>>(x,  xb,  nx);
  cast_f32_bf16<<<nw / 4 / 256, 256, 0, stream>>>(wq, wqb, nw);
  cast_f32_bf16<<<nw / 4 / 256, 256, 0, stream>>>(wk, wkb, nw);
  cast_f32_bf16<<<nw / 4 / 256, 256, 0, stream>>>(wvp, wvb, nw);
  cast_f32_bf16<<<nw / 4 / 256, 256, 0, stream>>>(wo, wob, nw);

  dim3 g1(4096 / 128, 1024 / 128, 3);
  gemm_nt<0><<<g1, 256, 0, stream>>>(xb, wqb, wkb, wvb, bq, bk, bv,
                                     Qb, Kb, Vb, 4096, 1024, 1024);

  attn_win<<<dim3(S_LEN / 64, NHEADS, 2), 256, 0, stream>>>(Qb, Kb, Vb, Ob);

  dim3 g2(4096 / 128, 1024 / 128, 1);
  gemm_nt<1><<<g2, 256, 0, stream>>>(Ob, wob, wob, wob, bo, bo, bo,
                                     out, out, out, 4096, 1024, 1024);
}

// Round 2
// 97.556 us; speedup vs baseline: 1.0562x; 1.0562x over previous
//
#include <hip/hip_runtime.h>

#define S_LEN 2048
#define DMODEL 1024
#define NHEADS 16
#define WIN 256

typedef unsigned short u16;
typedef unsigned int u32;
typedef __attribute__((ext_vector_type(8))) __bf16 bf16x8;
typedef __attribute__((ext_vector_type(4))) float f32x4;
typedef __attribute__((ext_vector_type(8))) u16 u16x8;
typedef __attribute__((ext_vector_type(4))) u16 u16x4;

__device__ __forceinline__ u16 f2bf(float f) {
  u32 u = __builtin_bit_cast(u32, f);
  u += 0x7fffu + ((u >> 16) & 1u);   // round-to-nearest-even
  return (u16)(u >> 16);
}

#define GLDS16(g, l) __builtin_amdgcn_global_load_lds( \
    (const __attribute__((address_space(1))) void*)(g), \
    (__attribute__((address_space(3))) void*)(l), 16, 0, 0)

#define BAR() { asm volatile("" ::: "memory"); __builtin_amdgcn_s_barrier(); asm volatile("" ::: "memory"); }
#define LGKM0() { asm volatile("s_waitcnt lgkmcnt(0)" ::: "memory"); __builtin_amdgcn_sched_barrier(0); }
#define VMCNT(n) asm volatile("s_waitcnt vmcnt(" #n ")" ::: "memory")

// ---------------- fused cast f32 -> bf16 (x + 4 weights, one launch) ----------------
__global__ __launch_bounds__(256) void cast_all(
    const float* __restrict__ x, const float* __restrict__ wq, const float* __restrict__ wk,
    const float* __restrict__ wv, const float* __restrict__ wo,
    u16* __restrict__ xb, u16* __restrict__ wqb, u16* __restrict__ wkb,
    u16* __restrict__ wvb, u16* __restrict__ wob) {
  const int e = (blockIdx.x * 256 + threadIdx.x) * 4;
  const float* src; u16* dst; int off;
  if (e < (1 << 22)) { src = x; dst = xb; off = e; }
  else {
    int r = e - (1 << 22);
    int seg = r >> 20; off = r & ((1 << 20) - 1);
    src = (seg == 0) ? wq : (seg == 1) ? wk : (seg == 2) ? wv : wo;
    dst = (seg == 0) ? wqb : (seg == 1) ? wkb : (seg == 2) ? wvb : wob;
  }
  float4 v = *(const float4*)(src + off);
  u16x4 o = { f2bf(v.x), f2bf(v.y), f2bf(v.z), f2bf(v.w) };
  *(u16x4*)(dst + off) = o;
}

// ---------------- fused QKV: 256x256 tile, BK=64, 8 waves, 8-phase schedule ----------------
// C[4096, 3072] = A[4096,1024] * [Wq;Wk;Wv]^T + bias, written bf16 to Qo/Ko/Vo.
// T2 XOR swizzle (byte ^= (row&7)<<4) via inverse-swizzled global source (linear
// global_load_lds dest) + swizzled ds_read. Counted vmcnt gates (4 / 4,2 / 4,0),
// raw s_barriers (2/phase), setprio around each 16-MFMA quadrant.
__global__ __launch_bounds__(512, 2) void gemm_qkv_8ph(
    const u16* __restrict__ A,
    const u16* __restrict__ Wq, const u16* __restrict__ Wk, const u16* __restrict__ Wv,
    const float* __restrict__ bq, const float* __restrict__ bk, const float* __restrict__ bv,
    u16* __restrict__ Qo, u16* __restrict__ Ko, u16* __restrict__ Vo)
{
  constexpr int K = 1024;
  constexpr int NT = K / 64;           // 16 K-tiles

  __shared__ u16 AS[2][256 * 64];      // 64 KiB
  __shared__ u16 BS[2][256 * 64];      // 64 KiB

  const int t = threadIdx.x;
  const int lane = t & 63, lo = lane & 15, hi = lane >> 4;
  const int wid = t >> 6;
  const int wm = wid >> 2;             // 0..1  (row half of block tile)
  const int wn = wid & 3;              // 0..3  (col quarter)

  const int row0 = blockIdx.x * 256;
  const int by = blockIdx.y;           // 0..11
  const int wsel = by >> 2;
  const int col0 = (by & 3) * 256;     // local col within the selected weight
  const u16* Bt = (wsel == 0) ? Wq : (wsel == 1) ? Wk : Wv;
  const float* bias = (wsel == 0) ? bq : (wsel == 1) ? bk : bv;
  u16* C = (wsel == 0) ? Qo : (wsel == 1) ? Ko : Vo;

  // staging decode: linear LDS off (bytes, in half) = c*8192 + t*16
  //   row = c*64 + (t>>3);  slot = t&7;  logical col16 = slot ^ (row&7)
  const int s_r = t >> 3;
  const int s_col16 = (t & 7) ^ ((t >> 3) & 7);

  auto stageA = [&](int buf, int kt, int h) {
    #pragma unroll
    for (int c = 0; c < 2; ++c) {
      const int r = h * 128 + c * 64 + s_r;
      GLDS16(A + (size_t)(row0 + r) * K + kt * 64 + s_col16 * 8,
             (u16*)AS + buf * 16384 + h * 8192 + c * 4096 + t * 8);
    }
  };
  auto stageB = [&](int buf, int kt, int h) {
    #pragma unroll
    for (int c = 0; c < 2; ++c) {
      const int r = h * 128 + c * 64 + s_r;
      GLDS16(Bt + (size_t)(col0 + r) * K + kt * 64 + s_col16 * 8,
             (u16*)BS + buf * 16384 + h * 8192 + c * 4096 + t * 8);
    }
  };

  const int sx = lo & 7;               // row&7 for all fragment rows this lane reads
  auto rdA = [&](int buf, int rh, int q, int kk) -> bf16x8 {
    const int row = wm * 128 + rh * 64 + q * 16 + lo;
    const int byte = row * 128 + (((((kk << 2) + hi) ^ sx)) << 4);
    return *(const bf16x8*)((const char*)AS + buf * 32768 + byte);
  };
  auto rdB = [&](int buf, int ch, int c, int kk) -> bf16x8 {
    const int row = wn * 64 + ch * 32 + c * 16 + lo;
    const int byte = row * 128 + (((((kk << 2) + hi) ^ sx)) << 4);
    return *(const bf16x8*)((const char*)BS + buf * 32768 + byte);
  };

  f32x4 acc[8][4];
  #pragma unroll
  for (int i = 0; i < 8; ++i)
    #pragma unroll
    for (int j = 0; j < 4; ++j) acc[i][j] = (f32x4)0.0f;

  bf16x8 a[4][2], b0[2][2], b1[2][2];

  // prologue: stage tile 0 in drain order A0, B0, B1, A1
  stageA(0, 0, 0); stageB(0, 0, 0); stageB(0, 0, 1); stageA(0, 0, 1);
  VMCNT(4);                            // A0,B0 landed
  BAR();

  for (int kt = 0; kt < NT; ++kt) {
    const int buf = kt & 1;
    const bool nx = (kt + 1 < NT);

    // ---- P1: reads A-half0 + B-half0; stage A0(next); MFMA Q(rh=0,ch=0) ----
    #pragma unroll
    for (int q = 0; q < 4; ++q) { a[q][0] = rdA(buf, 0, q, 0); a[q][1] = rdA(buf, 0, q, 1); }
    #pragma unroll
    for (int c = 0; c < 2; ++c) { b0[c][0] = rdB(buf, 0, c, 0); b0[c][1] = rdB(buf, 0, c, 1); }
    if (nx) stageA(buf ^ 1, kt + 1, 0);
    if (nx) { VMCNT(4); } else { VMCNT(2); }       // gate P2's B1
    BAR();
    LGKM0();
    __builtin_amdgcn_s_setprio(1);
    #pragma unroll
    for (int q = 0; q < 4; ++q)
      #pragma unroll
      for (int c = 0; c < 2; ++c)
        #pragma unroll
        for (int kk = 0; kk < 2; ++kk)
          acc[q][c] = __builtin_amdgcn_mfma_f32_16x16x32_bf16(a[q][kk], b0[c][kk], acc[q][c], 0, 0, 0);
    __builtin_amdgcn_s_setprio(0);
    BAR();

    // ---- P2: reads B-half1; stage B0(next); MFMA Q(0,1) ----
    #pragma unroll
    for (int c = 0; c < 2; ++c) { b1[c][0] = rdB(buf, 1, c, 0); b1[c][1] = rdB(buf, 1, c, 1); }
    if (nx) stageB(buf ^ 1, kt + 1, 0);
    if (nx) { VMCNT(4); } else { VMCNT(0); }       // gate P3's A1
    BAR();
    LGKM0();
    __builtin_amdgcn_s_setprio(1);
    #pragma unroll
    for (int q = 0; q < 4; ++q)
      #pragma unroll
      for (int c = 0; c < 2; ++c)
        #pragma unroll
        for (int kk = 0; kk < 2; ++kk)
          acc[q][2 + c] = __builtin_amdgcn_mfma_f32_16x16x32_bf16(a[q][kk], b1[c][kk], acc[q][2 + c], 0, 0, 0);
    __builtin_amdgcn_s_setprio(0);
    BAR();

    // ---- P3: reads A-half1 (overwrites a); stage B1(next); MFMA Q(1,1) ----
    #pragma unroll
    for (int q = 0; q < 4; ++q) { a[q][0] = rdA(buf, 1, q, 0); a[q][1] = rdA(buf, 1, q, 1); }
    if (nx) stageB(buf ^ 1, kt + 1, 1);
    BAR();
    LGKM0();
    __builtin_amdgcn_s_setprio(1);
    #pragma unroll
    for (int q = 0; q < 4; ++q)
      #pragma unroll
      for (int c = 0; c < 2; ++c)
        #pragma unroll
        for (int kk = 0; kk < 2; ++kk)
          acc[4 + q][2 + c] = __builtin_amdgcn_mfma_f32_16x16x32_bf16(a[q][kk], b1[c][kk], acc[4 + q][2 + c], 0, 0, 0);
    __builtin_amdgcn_s_setprio(0);
    BAR();

    // ---- P4: no reads; stage A1(next); MFMA Q(1,0); gate next P1's A0,B0 ----
    if (nx) stageA(buf ^ 1, kt + 1, 1);
    if (nx) VMCNT(4);
    BAR();
    __builtin_amdgcn_s_setprio(1);
    #pragma unroll
    for (int q = 0; q < 4; ++q)
      #pragma unroll
      for (int c = 0; c < 2; ++c)
        #pragma unroll
        for (int kk = 0; kk < 2; ++kk)
          acc[4 + q][c] = __builtin_amdgcn_mfma_f32_16x16x32_bf16(a[q][kk], b0[c][kk], acc[4 + q][c], 0, 0, 0);
    __builtin_amdgcn_s_setprio(0);
    BAR();
  }

  // epilogue
  #pragma unroll
  for (int mi = 0; mi < 8; ++mi) {
    #pragma unroll
    for (int ni = 0; ni < 4; ++ni) {
      const int col = col0 + wn * 64 + ni * 16 + lo;
      const float bb = bias[col];
      #pragma unroll
      for (int r = 0; r < 4; ++r) {
        const int row = row0 + wm * 128 + mi * 16 + hi * 4 + r;
        C[(size_t)row * DMODEL + col] = f2bf(acc[mi][ni][r] + bb);
      }
    }
  }
}

// ---------------- out-proj NT GEMM (128^2, 2-phase) ----------------
__global__ __launch_bounds__(256) void gemm_out(
    const u16* __restrict__ A, const u16* __restrict__ Bt,
    const float* __restrict__ bias, float* __restrict__ C,
    const int M, const int N, const int K)
{
  __shared__ u16 As[2][128 * 32];
  __shared__ u16 Bs[2][128 * 32];

  const int t = threadIdx.x;
  const int row0 = blockIdx.x * 128;
  const int col0 = blockIdx.y * 128;
  const int lane = t & 63, lo = lane & 15, hi = lane >> 4;
  const int wv = t >> 6;
  const int wr = (wv >> 1) * 64, wc = (wv & 1) * 64;

  f32x4 acc[4][4];
  #pragma unroll
  for (int i = 0; i < 4; ++i)
    #pragma unroll
    for (int j = 0; j < 4; ++j) acc[i][j] = (f32x4)0.0f;

  const int NTk = K >> 5;

  auto stage = [&](int buf, int kt) {
    const int kof = kt * 32;
    #pragma unroll
    for (int c = 0; c < 2; ++c) {
      const int off = t * 16 + c * 4096;
      const int r = off >> 6;
      const int ke = (off & 63) >> 1;
      GLDS16(A  + (size_t)(row0 + r) * K + (kof + ke), (u16*)As + buf * (128 * 32) + (off >> 1));
      GLDS16(Bt + (size_t)(col0 + r) * K + (kof + ke), (u16*)Bs + buf * (128 * 32) + (off >> 1));
    }
  };

  stage(0, 0);
  int cur = 0;
  for (int kt = 0; kt < NTk; ++kt) {
    __syncthreads();
    if (kt + 1 < NTk) stage(cur ^ 1, kt + 1);
    bf16x8 af[4], bfr[4];
    #pragma unroll
    for (int mi = 0; mi < 4; ++mi)
      af[mi] = *(const bf16x8*)&As[cur][(wr + mi * 16 + lo) * 32 + hi * 8];
    #pragma unroll
    for (int ni = 0; ni < 4; ++ni)
      bfr[ni] = *(const bf16x8*)&Bs[cur][(wc + ni * 16 + lo) * 32 + hi * 8];
    #pragma unroll
    for (int mi = 0; mi < 4; ++mi)
      #pragma unroll
      for (int ni = 0; ni < 4; ++ni)
        acc[mi][ni] = __builtin_amdgcn_mfma_f32_16x16x32_bf16(af[mi], bfr[ni], acc[mi][ni], 0, 0, 0);
    cur ^= 1;
  }

  #pragma unroll
  for (int mi = 0; mi < 4; ++mi) {
    #pragma unroll
    for (int ni = 0; ni < 4; ++ni) {
      const int col = col0 + wc + ni * 16 + lo;
      const float bv = bias[col];
      #pragma unroll
      for (int r = 0; r < 4; ++r) {
        const int row = row0 + wr + mi * 16 + hi * 4 + r;
        C[(size_t)row * N + col] = acc[mi][ni][r] + bv;
      }
    }
  }
}

// ---------------- windowed causal attention (unchanged from R1) ----------------
__device__ __forceinline__ int swz(int row, int col) {   // ushort index, [*][64] tiles
  int byte = (row << 7) + (col << 1);
  byte ^= (row & 7) << 4;
  return byte >> 1;
}

__global__ __launch_bounds__(256) void attn_win(const u16* __restrict__ Q,
                                                const u16* __restrict__ K,
                                                const u16* __restrict__ V,
                                                u16* __restrict__ O) {
  const int qt = blockIdx.x, h = blockIdx.y, b = blockIdx.z;
  const int q0 = qt * 64;
  const int t = threadIdx.x;
  const int wv = t >> 6, lane = t & 63, lo = lane & 15, hi = lane >> 4;

  __shared__ u16 Qs[64 * 64];
  __shared__ u16 Ks[64 * 64];
  __shared__ u16 Vt[64 * 64];
  __shared__ u16 Ps[4][16 * 64];

  const size_t base = ((size_t)b * S_LEN) * DMODEL + h * 64;

  #pragma unroll
  for (int c = 0; c < 2; ++c) {
    const int off = t * 16 + c * 4096;
    const int r = off >> 7, ce = (off & 127) >> 1;
    GLDS16(Q + base + (size_t)(q0 + r) * DMODEL + ce, (u16*)Qs + (off >> 1));
  }
  __syncthreads();

  bf16x8 qf[2];
  #pragma unroll
  for (int kq = 0; kq < 2; ++kq)
    qf[kq] = *(const bf16x8*)&Qs[(wv * 16 + lo) * 64 + kq * 32 + hi * 8];

  f32x4 oacc[4];
  #pragma unroll
  for (int i = 0; i < 4; ++i) oacc[i] = (f32x4)0.0f;
  float m_r[4] = {-1e30f, -1e30f, -1e30f, -1e30f};
  float l_r[4] = {0.f, 0.f, 0.f, 0.f};

  const int vrow = t >> 2;
  const int vc0  = (t & 3) * 16;

  for (int kt = 0; kt < 5; ++kt) {
    const int kstart = q0 - 256 + kt * 64;
    if (kstart + 63 < 0) continue;
    __syncthreads();

    {
      const int jg = kstart + vrow;
      if (jg >= 0) {
        const u16* srcK = K + base + (size_t)jg * DMODEL + vc0;
        u16x8 k0 = *(const u16x8*)(srcK);
        u16x8 k1 = *(const u16x8*)(srcK + 8);
        *(u16x8*)&Ks[swz(vrow, vc0)]     = k0;
        *(u16x8*)&Ks[swz(vrow, vc0 + 8)] = k1;
        const u16* srcV = V + base + (size_t)jg * DMODEL + vc0;
        u16x8 v0 = *(const u16x8*)(srcV);
        u16x8 v1 = *(const u16x8*)(srcV + 8);
        #pragma unroll
        for (int e = 0; e < 8; ++e) {
          Vt[swz(vc0 + e, vrow)]     = v0[e];
          Vt[swz(vc0 + 8 + e, vrow)] = v1[e];
        }
      } else {
        u16x8 z = (u16x8)0;
        *(u16x8*)&Ks[swz(vrow, vc0)]     = z;
        *(u16x8*)&Ks[swz(vrow, vc0 + 8)] = z;
        #pragma unroll
        for (int e = 0; e < 16; ++e) Vt[swz(vc0 + e, vrow)] = 0;
      }
    }
    __syncthreads();

    f32x4 sfr[4];
    #pragma unroll
    for (int ni = 0; ni < 4; ++ni) {
      sfr[ni] = (f32x4)0.0f;
      #pragma unroll
      for (int kq = 0; kq < 2; ++kq) {
        bf16x8 kf = *(const bf16x8*)&Ks[swz(ni * 16 + lo, kq * 32 + hi * 8)];
        sfr[ni] = __builtin_amdgcn_mfma_f32_16x16x32_bf16(qf[kq], kf, sfr[ni], 0, 0, 0);
      }
    }

    float sv[4][4], cmax[4] = {-1e30f, -1e30f, -1e30f, -1e30f};
    const int i0 = q0 + wv * 16 + hi * 4;
    #pragma unroll
    for (int ni = 0; ni < 4; ++ni) {
      const int j = kstart + ni * 16 + lo;
      #pragma unroll
      for (int r = 0; r < 4; ++r) {
        const int i = i0 + r;
        float x = sfr[ni][r] * 0.125f;
        const bool ok = (j >= 0) & (j <= i) & (i - j < WIN);
        x = ok ? x : -1e30f;
        sv[ni][r] = x;
        cmax[r] = fmaxf(cmax[r], x);
      }
    }
    #pragma unroll
    for (int d = 1; d < 16; d <<= 1) {
      #pragma unroll
      for (int r = 0; r < 4; ++r) cmax[r] = fmaxf(cmax[r], __shfl_xor(cmax[r], d));
    }

    float pr[4][4], rsum[4];
    #pragma unroll
    for (int r = 0; r < 4; ++r) {
      const float mnew = fmaxf(m_r[r], cmax[r]);
      const float sc = __expf(m_r[r] - mnew);
      m_r[r] = mnew;
      l_r[r] *= sc;
      #pragma unroll
      for (int ni = 0; ni < 4; ++ni) oacc[ni][r] *= sc;
      float s = 0.f;
      #pragma unroll
      for (int ni = 0; ni < 4; ++ni) {
        const float p = __expf(sv[ni][r] - mnew);
        pr[ni][r] = p;
        s += p;
      }
      rsum[r] = s;
    }
    #pragma unroll
    for (int d = 1; d < 16; d <<= 1) {
      #pragma unroll
      for (int r = 0; r < 4; ++r) rsum[r] += __shfl_xor(rsum[r], d);
    }
    #pragma unroll
    for (int r = 0; r < 4; ++r) l_r[r] += rsum[r];

    #pragma unroll
    for (int ni = 0; ni < 4; ++ni)
      #pragma unroll
      for (int r = 0; r < 4; ++r)
        Ps[wv][swz(hi * 4 + r, ni * 16 + lo)] = f2bf(pr[ni][r]);

    bf16x8 pa[2];
    #pragma unroll
    for (int kp = 0; kp < 2; ++kp)
      pa[kp] = *(const bf16x8*)&Ps[wv][swz(lo, kp * 32 + hi * 8)];
    #pragma unroll
    for (int ni = 0; ni < 4; ++ni) {
      #pragma unroll
      for (int kp = 0; kp < 2; ++kp) {
        bf16x8 vf = *(const bf16x8*)&Vt[swz(ni * 16 + lo, kp * 32 + hi * 8)];
        oacc[ni] = __builtin_amdgcn_mfma_f32_16x16x32_bf16(pa[kp], vf, oacc[ni], 0, 0, 0);
      }
    }
  }

  #pragma unroll
  for (int ni = 0; ni < 4; ++ni) {
    #pragma unroll
    for (int r = 0; r < 4; ++r) {
      const int row = q0 + wv * 16 + hi * 4 + r;
      O[base + (size_t)row * DMODEL + ni * 16 + lo] = f2bf(oacc[ni][r] / l_r[r]);
    }
  }
}

// ---------------- launch ----------------
extern "C" void kernel_launch(void* const* d_in, const int* in_sizes, int n_in,
                              void* d_out, int out_size, void* d_ws, size_t ws_size,
                              hipStream_t stream) {
  const float* x  = (const float*)d_in[0];
  const float* wq = (const float*)d_in[1];
  const float* bq = (const float*)d_in[2];
  const float* wk = (const float*)d_in[3];
  const float* bk = (const float*)d_in[4];
  const float* wvp = (const float*)d_in[5];
  const float* bv = (const float*)d_in[6];
  const float* wo = (const float*)d_in[7];
  const float* bo = (const float*)d_in[8];
  float* out = (float*)d_out;

  char* ws = (char*)d_ws;
  const size_t MB = 1024 * 1024;
  u16* xb  = (u16*)(ws);
  u16* wqb = (u16*)(ws + 8 * MB);
  u16* wkb = (u16*)(ws + 10 * MB);
  u16* wvb = (u16*)(ws + 12 * MB);
  u16* wob = (u16*)(ws + 14 * MB);
  u16* Qb  = (u16*)(ws + 16 * MB);
  u16* Kb  = (u16*)(ws + 24 * MB);
  u16* Vb  = (u16*)(ws + 32 * MB);
  u16* Ob  = (u16*)(ws + 40 * MB);   // ends at 48 MB

  // fused casts: 4M (x) + 4x1M (weights) f32 elements, 4/thread
  cast_all<<<8192, 256, 0, stream>>>(x, wq, wk, wvp, wo, xb, wqb, wkb, wvb, wob);

  gemm_qkv_8ph<<<dim3(16, 12), 512, 0, stream>>>(xb, wqb, wkb, wvb, bq, bk, bv, Qb, Kb, Vb);

  attn_win<<<dim3(S_LEN / 64, NHEADS, 2), 256, 0, stream>>>(Qb, Kb, Vb, Ob);

  gemm_out<<<dim3(32, 8), 256, 0, stream>>>(Ob, wob, bo, out, 4096, 1024, 1024);
}

// Round 3
// 95.935 us; speedup vs baseline: 1.0740x; 1.0169x over previous
//
#include <hip/hip_runtime.h>

#define S_LEN 2048
#define DMODEL 1024
#define NHEADS 16
#define WIN 256

typedef unsigned short u16;
typedef unsigned int u32;
typedef __attribute__((ext_vector_type(8))) __bf16 bf16x8;
typedef __attribute__((ext_vector_type(4))) float f32x4;
typedef __attribute__((ext_vector_type(8))) u16 u16x8;
typedef __attribute__((ext_vector_type(4))) u16 u16x4;

__device__ __forceinline__ u16 f2bf(float f) {
  u32 u = __builtin_bit_cast(u32, f);
  u += 0x7fffu + ((u >> 16) & 1u);   // round-to-nearest-even
  return (u16)(u >> 16);
}

#define GLDS16(g, l) __builtin_amdgcn_global_load_lds( \
    (const __attribute__((address_space(1))) void*)(g), \
    (__attribute__((address_space(3))) void*)(l), 16, 0, 0)

// ---------------- fused cast f32 -> bf16 (x + 4 weights, one launch) ----------------
__global__ __launch_bounds__(256) void cast_all(
    const float* __restrict__ x, const float* __restrict__ wq, const float* __restrict__ wk,
    const float* __restrict__ wv, const float* __restrict__ wo,
    u16* __restrict__ xb, u16* __restrict__ wqb, u16* __restrict__ wkb,
    u16* __restrict__ wvb, u16* __restrict__ wob) {
  const int e = (blockIdx.x * 256 + threadIdx.x) * 4;
  const float* src; u16* dst; int off;
  if (e < (1 << 22)) { src = x; dst = xb; off = e; }
  else {
    int r = e - (1 << 22);
    int seg = r >> 20; off = r & ((1 << 20) - 1);
    src = (seg == 0) ? wq : (seg == 1) ? wk : (seg == 2) ? wv : wo;
    dst = (seg == 0) ? wqb : (seg == 1) ? wkb : (seg == 2) ? wvb : wob;
  }
  float4 v = *(const float4*)(src + off);
  u16x4 o = { f2bf(v.x), f2bf(v.y), f2bf(v.z), f2bf(v.w) };
  *(u16x4*)(dst + off) = o;
}

// ---------------- NT GEMM (QKV): 128x128 tile, BK=32, 2-phase, z selects weight ----------------
__global__ __launch_bounds__(256) void gemm_nt(
    const u16* __restrict__ A,
    const u16* __restrict__ B0, const u16* __restrict__ B1, const u16* __restrict__ B2,
    const float* __restrict__ bias0, const float* __restrict__ bias1, const float* __restrict__ bias2,
    u16* __restrict__ C0, u16* __restrict__ C1, u16* __restrict__ C2,
    const int M, const int N, const int K)
{
  const u16* Bt; const float* bias; u16* C;
  if (blockIdx.z == 0)      { Bt = B0; bias = bias0; C = C0; }
  else if (blockIdx.z == 1) { Bt = B1; bias = bias1; C = C1; }
  else                      { Bt = B2; bias = bias2; C = C2; }

  __shared__ u16 As[2][128 * 32];
  __shared__ u16 Bs[2][128 * 32];

  const int t = threadIdx.x;
  const int row0 = blockIdx.x * 128;
  const int col0 = blockIdx.y * 128;
  const int lane = t & 63, lo = lane & 15, hi = lane >> 4;
  const int wv = t >> 6;
  const int wr = (wv >> 1) * 64, wc = (wv & 1) * 64;

  f32x4 acc[4][4];
  #pragma unroll
  for (int i = 0; i < 4; ++i)
    #pragma unroll
    for (int j = 0; j < 4; ++j) acc[i][j] = (f32x4)0.0f;

  const int NT = K >> 5;

  auto stage = [&](int buf, int kt) {
    const int kof = kt * 32;
    #pragma unroll
    for (int c = 0; c < 2; ++c) {
      const int off = t * 16 + c * 4096;     // byte offset in 128x32 bf16 tile (64B rows)
      const int r = off >> 6;
      const int ke = (off & 63) >> 1;
      GLDS16(A  + (size_t)(row0 + r) * K + (kof + ke), (u16*)As + buf * (128 * 32) + (off >> 1));
      GLDS16(Bt + (size_t)(col0 + r) * K + (kof + ke), (u16*)Bs + buf * (128 * 32) + (off >> 1));
    }
  };

  stage(0, 0);
  int cur = 0;
  for (int kt = 0; kt < NT; ++kt) {
    __syncthreads();
    if (kt + 1 < NT) stage(cur ^ 1, kt + 1);
    bf16x8 af[4], bfr[4];
    #pragma unroll
    for (int mi = 0; mi < 4; ++mi)
      af[mi] = *(const bf16x8*)&As[cur][(wr + mi * 16 + lo) * 32 + hi * 8];
    #pragma unroll
    for (int ni = 0; ni < 4; ++ni)
      bfr[ni] = *(const bf16x8*)&Bs[cur][(wc + ni * 16 + lo) * 32 + hi * 8];
    #pragma unroll
    for (int mi = 0; mi < 4; ++mi)
      #pragma unroll
      for (int ni = 0; ni < 4; ++ni)
        acc[mi][ni] = __builtin_amdgcn_mfma_f32_16x16x32_bf16(af[mi], bfr[ni], acc[mi][ni], 0, 0, 0);
    cur ^= 1;
  }

  #pragma unroll
  for (int mi = 0; mi < 4; ++mi) {
    #pragma unroll
    for (int ni = 0; ni < 4; ++ni) {
      const int col = col0 + wc + ni * 16 + lo;
      const float bv = bias[col];
      #pragma unroll
      for (int r = 0; r < 4; ++r) {
        const int row = row0 + wr + mi * 16 + hi * 4 + r;
        C[(size_t)row * N + col] = f2bf(acc[mi][ni][r] + bv);
      }
    }
  }
}

// ---------------- out-proj NT GEMM: 128x64 tile, BK=32, 2-phase, 512 blocks ----------------
// M=4096 N=1024 K=1024. 4 waves as 2x2, each wave owns 64x32. XCD-swizzled block id.
__global__ __launch_bounds__(256) void gemm_out64(
    const u16* __restrict__ A, const u16* __restrict__ Bt,
    const float* __restrict__ bias, float* __restrict__ C)
{
  constexpr int N = 1024, K = 1024;

  __shared__ u16 As[2][128 * 32];
  __shared__ u16 Bs[2][64 * 32];

  // bijective XCD swizzle: 512 blocks, 64 per XCD; each XCD gets bx in a
  // contiguous range of 4 (A-panel 1MB) x all by (whole B, 2MB) -> fits 4MB L2.
  int id = blockIdx.y * gridDim.x + blockIdx.x;      // 0..511
  int wgid = (id & 7) * 64 + (id >> 3);
  const int row0 = (wgid >> 4) * 128;                // bx = wgid/16 in 0..31
  const int col0 = (wgid & 15) * 64;                 // by = wgid%16 in 0..15

  const int t = threadIdx.x;
  const int lane = t & 63, lo = lane & 15, hi = lane >> 4;
  const int wv = t >> 6;
  const int wr = (wv >> 1) * 64, wc = (wv & 1) * 32;

  f32x4 acc[4][2];
  #pragma unroll
  for (int i = 0; i < 4; ++i)
    #pragma unroll
    for (int j = 0; j < 2; ++j) acc[i][j] = (f32x4)0.0f;

  auto stage = [&](int buf, int kt) {
    const int kof = kt * 32;
    #pragma unroll
    for (int c = 0; c < 2; ++c) {         // A: 128x32 = 8KB = 2 rounds
      const int off = t * 16 + c * 4096;
      const int r = off >> 6;
      const int ke = (off & 63) >> 1;
      GLDS16(A + (size_t)(row0 + r) * K + (kof + ke), (u16*)As + buf * (128 * 32) + (off >> 1));
    }
    {                                      // B: 64x32 = 4KB = 1 round
      const int off = t * 16;
      const int r = off >> 6;
      const int ke = (off & 63) >> 1;
      GLDS16(Bt + (size_t)(col0 + r) * K + (kof + ke), (u16*)Bs + buf * (64 * 32) + (off >> 1));
    }
  };

  stage(0, 0);
  int cur = 0;
  for (int kt = 0; kt < (K >> 5); ++kt) {
    __syncthreads();
    if (kt + 1 < (K >> 5)) stage(cur ^ 1, kt + 1);
    bf16x8 af[4], bfr[2];
    #pragma unroll
    for (int mi = 0; mi < 4; ++mi)
      af[mi] = *(const bf16x8*)&As[cur][(wr + mi * 16 + lo) * 32 + hi * 8];
    #pragma unroll
    for (int ni = 0; ni < 2; ++ni)
      bfr[ni] = *(const bf16x8*)&Bs[cur][(wc + ni * 16 + lo) * 32 + hi * 8];
    #pragma unroll
    for (int mi = 0; mi < 4; ++mi)
      #pragma unroll
      for (int ni = 0; ni < 2; ++ni)
        acc[mi][ni] = __builtin_amdgcn_mfma_f32_16x16x32_bf16(af[mi], bfr[ni], acc[mi][ni], 0, 0, 0);
    cur ^= 1;
  }

  #pragma unroll
  for (int mi = 0; mi < 4; ++mi) {
    #pragma unroll
    for (int ni = 0; ni < 2; ++ni) {
      const int col = col0 + wc + ni * 16 + lo;
      const float bv = bias[col];
      #pragma unroll
      for (int r = 0; r < 4; ++r) {
        const int row = row0 + wr + mi * 16 + hi * 4 + r;
        C[(size_t)row * N + col] = acc[mi][ni][r] + bv;
      }
    }
  }
}

// ---------------- windowed causal attention ----------------
__device__ __forceinline__ int swz(int row, int col) {   // ushort index, [*][64] tiles
  int byte = (row << 7) + (col << 1);
  byte ^= (row & 7) << 4;
  return byte >> 1;
}

__global__ __launch_bounds__(256) void attn_win(const u16* __restrict__ Q,
                                                const u16* __restrict__ K,
                                                const u16* __restrict__ V,
                                                u16* __restrict__ O) {
  const int qt = blockIdx.x, h = blockIdx.y, b = blockIdx.z;
  const int q0 = qt * 64;
  const int t = threadIdx.x;
  const int wv = t >> 6, lane = t & 63, lo = lane & 15, hi = lane >> 4;

  __shared__ u16 Qs[64 * 64];
  __shared__ u16 Ks[64 * 64];
  __shared__ u16 Vt[64 * 64];
  __shared__ u16 Ps[4][16 * 64];

  const size_t base = ((size_t)b * S_LEN) * DMODEL + h * 64;

  #pragma unroll
  for (int c = 0; c < 2; ++c) {
    const int off = t * 16 + c * 4096;
    const int r = off >> 7, ce = (off & 127) >> 1;
    GLDS16(Q + base + (size_t)(q0 + r) * DMODEL + ce, (u16*)Qs + (off >> 1));
  }
  __syncthreads();

  bf16x8 qf[2];
  #pragma unroll
  for (int kq = 0; kq < 2; ++kq)
    qf[kq] = *(const bf16x8*)&Qs[(wv * 16 + lo) * 64 + kq * 32 + hi * 8];

  f32x4 oacc[4];
  #pragma unroll
  for (int i = 0; i < 4; ++i) oacc[i] = (f32x4)0.0f;
  float m_r[4] = {-1e30f, -1e30f, -1e30f, -1e30f};
  float l_r[4] = {0.f, 0.f, 0.f, 0.f};

  const int vrow = t >> 2;
  const int vc0  = (t & 3) * 16;

  for (int kt = 0; kt < 5; ++kt) {
    const int kstart = q0 - 256 + kt * 64;
    if (kstart + 63 < 0) continue;
    __syncthreads();

    {
      const int jg = kstart + vrow;
      if (jg >= 0) {
        const u16* srcK = K + base + (size_t)jg * DMODEL + vc0;
        u16x8 k0 = *(const u16x8*)(srcK);
        u16x8 k1 = *(const u16x8*)(srcK + 8);
        *(u16x8*)&Ks[swz(vrow, vc0)]     = k0;
        *(u16x8*)&Ks[swz(vrow, vc0 + 8)] = k1;
        const u16* srcV = V + base + (size_t)jg * DMODEL + vc0;
        u16x8 v0 = *(const u16x8*)(srcV);
        u16x8 v1 = *(const u16x8*)(srcV + 8);
        #pragma unroll
        for (int e = 0; e < 8; ++e) {
          Vt[swz(vc0 + e, vrow)]     = v0[e];
          Vt[swz(vc0 + 8 + e, vrow)] = v1[e];
        }
      } else {
        u16x8 z = (u16x8)0;
        *(u16x8*)&Ks[swz(vrow, vc0)]     = z;
        *(u16x8*)&Ks[swz(vrow, vc0 + 8)] = z;
        #pragma unroll
        for (int e = 0; e < 16; ++e) Vt[swz(vc0 + e, vrow)] = 0;
      }
    }
    __syncthreads();

    f32x4 sfr[4];
    #pragma unroll
    for (int ni = 0; ni < 4; ++ni) {
      sfr[ni] = (f32x4)0.0f;
      #pragma unroll
      for (int kq = 0; kq < 2; ++kq) {
        bf16x8 kf = *(const bf16x8*)&Ks[swz(ni * 16 + lo, kq * 32 + hi * 8)];
        sfr[ni] = __builtin_amdgcn_mfma_f32_16x16x32_bf16(qf[kq], kf, sfr[ni], 0, 0, 0);
      }
    }

    float sv[4][4], cmax[4] = {-1e30f, -1e30f, -1e30f, -1e30f};
    const int i0 = q0 + wv * 16 + hi * 4;
    #pragma unroll
    for (int ni = 0; ni < 4; ++ni) {
      const int j = kstart + ni * 16 + lo;
      #pragma unroll
      for (int r = 0; r < 4; ++r) {
        const int i = i0 + r;
        float x = sfr[ni][r] * 0.125f;
        const bool ok = (j >= 0) & (j <= i) & (i - j < WIN);
        x = ok ? x : -1e30f;
        sv[ni][r] = x;
        cmax[r] = fmaxf(cmax[r], x);
      }
    }
    #pragma unroll
    for (int d = 1; d < 16; d <<= 1) {
      #pragma unroll
      for (int r = 0; r < 4; ++r) cmax[r] = fmaxf(cmax[r], __shfl_xor(cmax[r], d));
    }

    float pr[4][4], rsum[4];
    #pragma unroll
    for (int r = 0; r < 4; ++r) {
      const float mnew = fmaxf(m_r[r], cmax[r]);
      const float sc = __expf(m_r[r] - mnew);
      m_r[r] = mnew;
      l_r[r] *= sc;
      #pragma unroll
      for (int ni = 0; ni < 4; ++ni) oacc[ni][r] *= sc;
      float s = 0.f;
      #pragma unroll
      for (int ni = 0; ni < 4; ++ni) {
        const float p = __expf(sv[ni][r] - mnew);
        pr[ni][r] = p;
        s += p;
      }
      rsum[r] = s;
    }
    #pragma unroll
    for (int d = 1; d < 16; d <<= 1) {
      #pragma unroll
      for (int r = 0; r < 4; ++r) rsum[r] += __shfl_xor(rsum[r], d);
    }
    #pragma unroll
    for (int r = 0; r < 4; ++r) l_r[r] += rsum[r];

    #pragma unroll
    for (int ni = 0; ni < 4; ++ni)
      #pragma unroll
      for (int r = 0; r < 4; ++r)
        Ps[wv][swz(hi * 4 + r, ni * 16 + lo)] = f2bf(pr[ni][r]);

    bf16x8 pa[2];
    #pragma unroll
    for (int kp = 0; kp < 2; ++kp)
      pa[kp] = *(const bf16x8*)&Ps[wv][swz(lo, kp * 32 + hi * 8)];
    #pragma unroll
    for (int ni = 0; ni < 4; ++ni) {
      #pragma unroll
      for (int kp = 0; kp < 2; ++kp) {
        bf16x8 vf = *(const bf16x8*)&Vt[swz(ni * 16 + lo, kp * 32 + hi * 8)];
        oacc[ni] = __builtin_amdgcn_mfma_f32_16x16x32_bf16(pa[kp], vf, oacc[ni], 0, 0, 0);
      }
    }
  }

  #pragma unroll
  for (int ni = 0; ni < 4; ++ni) {
    #pragma unroll
    for (int r = 0; r < 4; ++r) {
      const int row = q0 + wv * 16 + hi * 4 + r;
      O[base + (size_t)row * DMODEL + ni * 16 + lo] = f2bf(oacc[ni][r] / l_r[r]);
    }
  }
}

// ---------------- launch ----------------
extern "C" void kernel_launch(void* const* d_in, const int* in_sizes, int n_in,
                              void* d_out, int out_size, void* d_ws, size_t ws_size,
                              hipStream_t stream) {
  const float* x  = (const float*)d_in[0];
  const float* wq = (const float*)d_in[1];
  const float* bq = (const float*)d_in[2];
  const float* wk = (const float*)d_in[3];
  const float* bk = (const float*)d_in[4];
  const float* wvp = (const float*)d_in[5];
  const float* bv = (const float*)d_in[6];
  const float* wo = (const float*)d_in[7];
  const float* bo = (const float*)d_in[8];
  float* out = (float*)d_out;

  char* ws = (char*)d_ws;
  const size_t MB = 1024 * 1024;
  u16* xb  = (u16*)(ws);
  u16* wqb = (u16*)(ws + 8 * MB);
  u16* wkb = (u16*)(ws + 10 * MB);
  u16* wvb = (u16*)(ws + 12 * MB);
  u16* wob = (u16*)(ws + 14 * MB);
  u16* Qb  = (u16*)(ws + 16 * MB);
  u16* Kb  = (u16*)(ws + 24 * MB);
  u16* Vb  = (u16*)(ws + 32 * MB);
  u16* Ob  = (u16*)(ws + 40 * MB);   // ends at 48 MB

  cast_all<<<8192, 256, 0, stream>>>(x, wq, wk, wvp, wo, xb, wqb, wkb, wvb, wob);

  dim3 g1(4096 / 128, 1024 / 128, 3);
  gemm_nt<<<g1, 256, 0, stream>>>(xb, wqb, wkb, wvb, bq, bk, bv,
                                  Qb, Kb, Vb, 4096, 1024, 1024);

  attn_win<<<dim3(S_LEN / 64, NHEADS, 2), 256, 0, stream>>>(Qb, Kb, Vb, Ob);

  gemm_out64<<<dim3(32, 16), 256, 0, stream>>>(Ob, wob, bo, out);
}

// Round 5
// 94.707 us; speedup vs baseline: 1.0880x; 1.0130x over previous
//
#include <hip/hip_runtime.h>

#define S_LEN 2048
#define DMODEL 1024
#define NHEADS 16
#define WIN 256

typedef unsigned short u16;
typedef unsigned int u32;
typedef __attribute__((ext_vector_type(8))) __bf16 bf16x8;
typedef __attribute__((ext_vector_type(4))) float f32x4;
typedef __attribute__((ext_vector_type(8))) u16 u16x8;
typedef __attribute__((ext_vector_type(4))) u16 u16x4;

__device__ __forceinline__ u16 f2bf(float f) {
  u32 u = __builtin_bit_cast(u32, f);
  u += 0x7fffu + ((u >> 16) & 1u);   // round-to-nearest-even
  return (u16)(u >> 16);
}

#define GLDS16(g, l) __builtin_amdgcn_global_load_lds( \
    (const __attribute__((address_space(1))) void*)(g), \
    (__attribute__((address_space(3))) void*)(l), 16, 0, 0)

// ---------------- fused cast f32 -> bf16 (x + 4 weights, one launch) ----------------
__global__ __launch_bounds__(256) void cast_all(
    const float* __restrict__ x, const float* __restrict__ wq, const float* __restrict__ wk,
    const float* __restrict__ wv, const float* __restrict__ wo,
    u16* __restrict__ xb, u16* __restrict__ wqb, u16* __restrict__ wkb,
    u16* __restrict__ wvb, u16* __restrict__ wob) {
  const int e = (blockIdx.x * 256 + threadIdx.x) * 4;
  const float* src; u16* dst; int off;
  if (e < (1 << 22)) { src = x; dst = xb; off = e; }
  else {
    int r = e - (1 << 22);
    int seg = r >> 20; off = r & ((1 << 20) - 1);
    src = (seg == 0) ? wq : (seg == 1) ? wk : (seg == 2) ? wv : wo;
    dst = (seg == 0) ? wqb : (seg == 1) ? wkb : (seg == 2) ? wvb : wob;
  }
  float4 v = *(const float4*)(src + off);
  u16x4 o = { f2bf(v.x), f2bf(v.y), f2bf(v.z), f2bf(v.w) };
  *(u16x4*)(dst + off) = o;
}

// ---------------- NT GEMM (QKV): 128x128 tile, BK=32, 2-phase, z selects weight ----------------
__global__ __launch_bounds__(256) void gemm_nt(
    const u16* __restrict__ A,
    const u16* __restrict__ B0, const u16* __restrict__ B1, const u16* __restrict__ B2,
    const float* __restrict__ bias0, const float* __restrict__ bias1, const float* __restrict__ bias2,
    u16* __restrict__ C0, u16* __restrict__ C1, u16* __restrict__ C2,
    const int M, const int N, const int K)
{
  const u16* Bt; const float* bias; u16* C;
  if (blockIdx.z == 0)      { Bt = B0; bias = bias0; C = C0; }
  else if (blockIdx.z == 1) { Bt = B1; bias = bias1; C = C1; }
  else                      { Bt = B2; bias = bias2; C = C2; }

  __shared__ u16 As[2][128 * 32];
  __shared__ u16 Bs[2][128 * 32];

  const int t = threadIdx.x;
  const int row0 = blockIdx.x * 128;
  const int col0 = blockIdx.y * 128;
  const int lane = t & 63, lo = lane & 15, hi = lane >> 4;
  const int wv = t >> 6;
  const int wr = (wv >> 1) * 64, wc = (wv & 1) * 64;

  f32x4 acc[4][4];
  #pragma unroll
  for (int i = 0; i < 4; ++i)
    #pragma unroll
    for (int j = 0; j < 4; ++j) acc[i][j] = (f32x4)0.0f;

  const int NT = K >> 5;

  auto stage = [&](int buf, int kt) {
    const int kof = kt * 32;
    #pragma unroll
    for (int c = 0; c < 2; ++c) {
      const int off = t * 16 + c * 4096;
      const int r = off >> 6;
      const int ke = (off & 63) >> 1;
      GLDS16(A  + (size_t)(row0 + r) * K + (kof + ke), (u16*)As + buf * (128 * 32) + (off >> 1));
      GLDS16(Bt + (size_t)(col0 + r) * K + (kof + ke), (u16*)Bs + buf * (128 * 32) + (off >> 1));
    }
  };

  stage(0, 0);
  int cur = 0;
  for (int kt = 0; kt < NT; ++kt) {
    __syncthreads();
    if (kt + 1 < NT) stage(cur ^ 1, kt + 1);
    bf16x8 af[4], bfr[4];
    #pragma unroll
    for (int mi = 0; mi < 4; ++mi)
      af[mi] = *(const bf16x8*)&As[cur][(wr + mi * 16 + lo) * 32 + hi * 8];
    #pragma unroll
    for (int ni = 0; ni < 4; ++ni)
      bfr[ni] = *(const bf16x8*)&Bs[cur][(wc + ni * 16 + lo) * 32 + hi * 8];
    #pragma unroll
    for (int mi = 0; mi < 4; ++mi)
      #pragma unroll
      for (int ni = 0; ni < 4; ++ni)
        acc[mi][ni] = __builtin_amdgcn_mfma_f32_16x16x32_bf16(af[mi], bfr[ni], acc[mi][ni], 0, 0, 0);
    cur ^= 1;
  }

  #pragma unroll
  for (int mi = 0; mi < 4; ++mi) {
    #pragma unroll
    for (int ni = 0; ni < 4; ++ni) {
      const int col = col0 + wc + ni * 16 + lo;
      const float bv = bias[col];
      #pragma unroll
      for (int r = 0; r < 4; ++r) {
        const int row = row0 + wr + mi * 16 + hi * 4 + r;
        C[(size_t)row * N + col] = f2bf(acc[mi][ni][r] + bv);
      }
    }
  }
}

// ---------------- out-proj NT GEMM: 128x64 tile, BK=32, 2-phase, 512 blocks ----------------
__global__ __launch_bounds__(256) void gemm_out64(
    const u16* __restrict__ A, const u16* __restrict__ Bt,
    const float* __restrict__ bias, float* __restrict__ C)
{
  constexpr int N = 1024, K = 1024;

  __shared__ u16 As[2][128 * 32];
  __shared__ u16 Bs[2][64 * 32];

  int id = blockIdx.y * gridDim.x + blockIdx.x;      // 0..511
  int wgid = (id & 7) * 64 + (id >> 3);
  const int row0 = (wgid >> 4) * 128;
  const int col0 = (wgid & 15) * 64;

  const int t = threadIdx.x;
  const int lane = t & 63, lo = lane & 15, hi = lane >> 4;
  const int wv = t >> 6;
  const int wr = (wv >> 1) * 64, wc = (wv & 1) * 32;

  f32x4 acc[4][2];
  #pragma unroll
  for (int i = 0; i < 4; ++i)
    #pragma unroll
    for (int j = 0; j < 2; ++j) acc[i][j] = (f32x4)0.0f;

  auto stage = [&](int buf, int kt) {
    const int kof = kt * 32;
    #pragma unroll
    for (int c = 0; c < 2; ++c) {
      const int off = t * 16 + c * 4096;
      const int r = off >> 6;
      const int ke = (off & 63) >> 1;
      GLDS16(A + (size_t)(row0 + r) * K + (kof + ke), (u16*)As + buf * (128 * 32) + (off >> 1));
    }
    {
      const int off = t * 16;
      const int r = off >> 6;
      const int ke = (off & 63) >> 1;
      GLDS16(Bt + (size_t)(col0 + r) * K + (kof + ke), (u16*)Bs + buf * (64 * 32) + (off >> 1));
    }
  };

  stage(0, 0);
  int cur = 0;
  for (int kt = 0; kt < (K >> 5); ++kt) {
    __syncthreads();
    if (kt + 1 < (K >> 5)) stage(cur ^ 1, kt + 1);
    bf16x8 af[4], bfr[2];
    #pragma unroll
    for (int mi = 0; mi < 4; ++mi)
      af[mi] = *(const bf16x8*)&As[cur][(wr + mi * 16 + lo) * 32 + hi * 8];
    #pragma unroll
    for (int ni = 0; ni < 2; ++ni)
      bfr[ni] = *(const bf16x8*)&Bs[cur][(wc + ni * 16 + lo) * 32 + hi * 8];
    #pragma unroll
    for (int mi = 0; mi < 4; ++mi)
      #pragma unroll
      for (int ni = 0; ni < 2; ++ni)
        acc[mi][ni] = __builtin_amdgcn_mfma_f32_16x16x32_bf16(af[mi], bfr[ni], acc[mi][ni], 0, 0, 0);
    cur ^= 1;
  }

  #pragma unroll
  for (int mi = 0; mi < 4; ++mi) {
    #pragma unroll
    for (int ni = 0; ni < 2; ++ni) {
      const int col = col0 + wc + ni * 16 + lo;
      const float bv = bias[col];
      #pragma unroll
      for (int r = 0; r < 4; ++r) {
        const int row = row0 + wr + mi * 16 + hi * 4 + r;
        C[(size_t)row * N + col] = acc[mi][ni][r] + bv;
      }
    }
  }
}

// ---------------- windowed causal attention (R3 PV path + dbuf/T14 + fixed V swizzle) ----------------
__device__ __forceinline__ int swzK(int row, int col) {   // K/P tiles: row=j(or i), col=d(or j)
  int byte = (row << 7) + (col << 1);
  byte ^= (row & 7) << 4;
  return byte >> 1;
}
// Vt tile: row = d (0..63), col = j (0..63). Extra XOR term spreads the
// write-side banks (writer owns fixed j, 16 d's): bank = (t>>3) | ((t&3)<<3).
__device__ __forceinline__ int swzV(int d, int j) {
  int byte = (d << 7) + (j << 1);
  byte ^= ((d & 7) << 4) ^ (((d >> 4) & 3) << 5);
  return byte >> 1;
}

__global__ __launch_bounds__(256) void attn_win(const u16* __restrict__ Q,
                                                const u16* __restrict__ K,
                                                const u16* __restrict__ V,
                                                u16* __restrict__ O) {
  const int qt = blockIdx.x, h = blockIdx.y, b = blockIdx.z;
  const int q0 = qt * 64;
  const int t = threadIdx.x;
  const int wv = t >> 6, lane = t & 63, lo = lane & 15, hi = lane >> 4;

  __shared__ u16 Qs[64 * 64];
  __shared__ u16 Ks[2][64 * 64];
  __shared__ u16 Vt[2][64 * 64];
  __shared__ u16 Ps[4][16 * 64];

  const size_t base = ((size_t)b * S_LEN) * DMODEL + h * 64;

  // Q tile -> LDS (linear, via global_load_lds), read once into regs
  #pragma unroll
  for (int c = 0; c < 2; ++c) {
    const int off = t * 16 + c * 4096;
    const int r = off >> 7, ce = (off & 127) >> 1;
    GLDS16(Q + base + (size_t)(q0 + r) * DMODEL + ce, (u16*)Qs + (off >> 1));
  }

  const int vrow = t >> 2;          // j within chunk
  const int vc0  = (t & 3) * 16;    // d group
  const int ktmin = max(0, (256 - q0) >> 6);

  u16x8 kra, krb, vra, vrb;
  auto issue = [&](int kt) {
    const int jg = q0 - 256 + kt * 64 + vrow;
    if (jg >= 0) {
      const u16* sk = K + base + (size_t)jg * DMODEL + vc0;
      kra = *(const u16x8*)sk; krb = *(const u16x8*)(sk + 8);
      const u16* sv = V + base + (size_t)jg * DMODEL + vc0;
      vra = *(const u16x8*)sv; vrb = *(const u16x8*)(sv + 8);
    } else {
      kra = (u16x8)0; krb = (u16x8)0; vra = (u16x8)0; vrb = (u16x8)0;
    }
  };
  auto commit = [&](int buf) {
    *(u16x8*)&Ks[buf][swzK(vrow, vc0)]     = kra;
    *(u16x8*)&Ks[buf][swzK(vrow, vc0 + 8)] = krb;
    #pragma unroll
    for (int e = 0; e < 8; ++e) {
      Vt[buf][swzV(vc0 + e, vrow)]     = vra[e];
      Vt[buf][swzV(vc0 + 8 + e, vrow)] = vrb[e];
    }
  };

  issue(ktmin);
  commit(0);
  __syncthreads();      // Qs (vmcnt) + chunk0 K/V writes (lgkm) visible

  bf16x8 qf[2];
  #pragma unroll
  for (int kq = 0; kq < 2; ++kq)
    qf[kq] = *(const bf16x8*)&Qs[(wv * 16 + lo) * 64 + kq * 32 + hi * 8];

  f32x4 oacc[4];
  #pragma unroll
  for (int i = 0; i < 4; ++i) oacc[i] = (f32x4)0.0f;
  float m_r[4] = {-1e30f, -1e30f, -1e30f, -1e30f};
  float l_r[4] = {0.f, 0.f, 0.f, 0.f};

  int cur = 0;
  for (int kt = ktmin; kt < 5; ++kt) {
    const int kstart = q0 - 256 + kt * 64;
    if (kt < 4) issue(kt + 1);           // T14: next chunk's loads in flight

    // S = Q K^T
    f32x4 sfr[4];
    #pragma unroll
    for (int ni = 0; ni < 4; ++ni) {
      sfr[ni] = (f32x4)0.0f;
      #pragma unroll
      for (int kq = 0; kq < 2; ++kq) {
        bf16x8 kf = *(const bf16x8*)&Ks[cur][swzK(ni * 16 + lo, kq * 32 + hi * 8)];
        sfr[ni] = __builtin_amdgcn_mfma_f32_16x16x32_bf16(qf[kq], kf, sfr[ni], 0, 0, 0);
      }
    }

    // mask + scale + per-row chunk max
    float sv[4][4], cmax[4] = {-1e30f, -1e30f, -1e30f, -1e30f};
    const int i0 = q0 + wv * 16 + hi * 4;
    #pragma unroll
    for (int ni = 0; ni < 4; ++ni) {
      const int j = kstart + ni * 16 + lo;
      #pragma unroll
      for (int r = 0; r < 4; ++r) {
        const int i = i0 + r;
        float x = sfr[ni][r] * 0.125f;
        const bool ok = (j >= 0) & (j <= i) & (i - j < WIN);
        x = ok ? x : -1e30f;
        sv[ni][r] = x;
        cmax[r] = fmaxf(cmax[r], x);
      }
    }
    #pragma unroll
    for (int d = 1; d < 16; d <<= 1) {
      #pragma unroll
      for (int r = 0; r < 4; ++r) cmax[r] = fmaxf(cmax[r], __shfl_xor(cmax[r], d));
    }

    // online-softmax update
    float pr[4][4], rsum[4];
    #pragma unroll
    for (int r = 0; r < 4; ++r) {
      const float mnew = fmaxf(m_r[r], cmax[r]);
      const float sc = __expf(m_r[r] - mnew);
      m_r[r] = mnew;
      l_r[r] *= sc;
      #pragma unroll
      for (int ni = 0; ni < 4; ++ni) oacc[ni][r] *= sc;
      float s = 0.f;
      #pragma unroll
      for (int ni = 0; ni < 4; ++ni) {
        const float p = __expf(sv[ni][r] - mnew);
        pr[ni][r] = p;
        s += p;
      }
      rsum[r] = s;
    }
    #pragma unroll
    for (int d = 1; d < 16; d <<= 1) {
      #pragma unroll
      for (int r = 0; r < 4; ++r) rsum[r] += __shfl_xor(rsum[r], d);
    }
    #pragma unroll
    for (int r = 0; r < 4; ++r) l_r[r] += rsum[r];

    // P -> per-wave LDS (C-layout write), re-read as A-fragments
    #pragma unroll
    for (int ni = 0; ni < 4; ++ni)
      #pragma unroll
      for (int r = 0; r < 4; ++r)
        Ps[wv][swzK(hi * 4 + r, ni * 16 + lo)] = f2bf(pr[ni][r]);

    bf16x8 pa[2];
    #pragma unroll
    for (int kp = 0; kp < 2; ++kp)
      pa[kp] = *(const bf16x8*)&Ps[wv][swzK(lo, kp * 32 + hi * 8)];

    // PV: vector b128 reads from transposed Vt
    #pragma unroll
    for (int ni = 0; ni < 4; ++ni) {
      #pragma unroll
      for (int kp = 0; kp < 2; ++kp) {
        bf16x8 vf = *(const bf16x8*)&Vt[cur][swzV(ni * 16 + lo, kp * 32 + hi * 8)];
        oacc[ni] = __builtin_amdgcn_mfma_f32_16x16x32_bf16(pa[kp], vf, oacc[ni], 0, 0, 0);
      }
    }

    if (kt < 4) commit(cur ^ 1);         // vmcnt wait lands here, writes buf^1
    __syncthreads();                      // one barrier per chunk
    cur ^= 1;
  }

  #pragma unroll
  for (int ni = 0; ni < 4; ++ni) {
    #pragma unroll
    for (int r = 0; r < 4; ++r) {
      const int row = q0 + wv * 16 + hi * 4 + r;
      O[base + (size_t)row * DMODEL + ni * 16 + lo] = f2bf(oacc[ni][r] / l_r[r]);
    }
  }
}

// ---------------- launch ----------------
extern "C" void kernel_launch(void* const* d_in, const int* in_sizes, int n_in,
                              void* d_out, int out_size, void* d_ws, size_t ws_size,
                              hipStream_t stream) {
  const float* x  = (const float*)d_in[0];
  const float* wq = (const float*)d_in[1];
  const float* bq = (const float*)d_in[2];
  const float* wk = (const float*)d_in[3];
  const float* bk = (const float*)d_in[4];
  const float* wvp = (const float*)d_in[5];
  const float* bv = (const float*)d_in[6];
  const float* wo = (const float*)d_in[7];
  const float* bo = (const float*)d_in[8];
  float* out = (float*)d_out;

  char* ws = (char*)d_ws;
  const size_t MB = 1024 * 1024;
  u16* xb  = (u16*)(ws);
  u16* wqb = (u16*)(ws + 8 * MB);
  u16* wkb = (u16*)(ws + 10 * MB);
  u16* wvb = (u16*)(ws + 12 * MB);
  u16* wob = (u16*)(ws + 14 * MB);
  u16* Qb  = (u16*)(ws + 16 * MB);
  u16* Kb  = (u16*)(ws + 24 * MB);
  u16* Vb  = (u16*)(ws + 32 * MB);
  u16* Ob  = (u16*)(ws + 40 * MB);   // ends at 48 MB

  cast_all<<<8192, 256, 0, stream>>>(x, wq, wk, wvp, wo, xb, wqb, wkb, wvb, wob);

  dim3 g1(4096 / 128, 1024 / 128, 3);
  gemm_nt<<<g1, 256, 0, stream>>>(xb, wqb, wkb, wvb, bq, bk, bv,
                                  Qb, Kb, Vb, 4096, 1024, 1024);

  attn_win<<<dim3(S_LEN / 64, NHEADS, 2), 256, 0, stream>>>(Qb, Kb, Vb, Ob);

  gemm_out64<<<dim3(32, 16), 256, 0, stream>>>(Ob, wob, bo, out);
}